// Round 7
// baseline (1937.733 us; speedup 1.0000x reference)
//
#include <hip/hip_runtime.h>

#define TT 2048
#define BB 64

typedef _Float16 v2h __attribute__((ext_vector_type(2)));

__device__ __forceinline__ float frcp(float x) { return __builtin_amdgcn_rcpf(x); }
__device__ __forceinline__ float fsig(float x) { return frcp(1.f + __expf(-x)); }
__device__ __forceinline__ float ftan(float x) { return 1.f - 2.f * frcp(1.f + __expf(2.f * x)); }

#if __has_builtin(__builtin_amdgcn_fdot2)
#define FDOT2(a, b, c) __builtin_amdgcn_fdot2((a), (b), (c), false)
#else
#define FDOT2(a, b, c) ((c) + (float)(a).x * (float)(b).x + (float)(a).y * (float)(b).y)
#endif

// Canonical GCN wave64 sum-reduction via DPP (verified R4/R5):
// row_shr:1,2,4,8 then row_bcast:15, row_bcast:31; total lands in lane 63.
#define DPPADD(x, ctrl)                                                        \
  (x) += __builtin_bit_cast(float, __builtin_amdgcn_update_dpp(                \
             0, __builtin_bit_cast(int, (x)), (ctrl), 0xf, 0xf, true))

__device__ __forceinline__ float wave_sum64(float x) {
  DPPADD(x, 0x111);  // row_shr:1
  DPPADD(x, 0x112);  // row_shr:2
  DPPADD(x, 0x114);  // row_shr:4
  DPPADD(x, 0x118);  // row_shr:8
  DPPADD(x, 0x142);  // row_bcast:15
  DPPADD(x, 0x143);  // row_bcast:31
  return __builtin_bit_cast(
      float, __builtin_amdgcn_readlane(__builtin_bit_cast(int, x), 63));
}

// G[(b*Tc+tt)*256 + g] = sum_k X[...] * W_ih[g,k] + b_ih[g] + b_hh[g]
// Tiled fp32 GEMM (R5-proven, unfused): grid=(Tc,4), block=256, tile 64x64.
__global__ __launch_bounds__(256) void gates_gemm(const float* __restrict__ X,
                                                  const float* __restrict__ W,
                                                  const float* __restrict__ bih,
                                                  const float* __restrict__ bhh,
                                                  float* __restrict__ G,
                                                  int t0, int Tc) {
  __shared__ __align__(16) float As[32][64];  // As[k][m]
  __shared__ __align__(16) float Bs[32][64];  // Bs[k][n]
  const int tid = threadIdx.x;
  const int m0 = blockIdx.x * 64;
  const int n0 = blockIdx.y * 64;
  const int bb = m0 / Tc;
  const int tt0 = m0 - bb * Tc;
  const int tx = tid & 15, ty = tid >> 4;
  const int r  = tid >> 2;
  const int kq = (tid & 3) * 8;
  const float* xrow = X + ((size_t)(bb * TT + t0 + tt0 + r)) * 256 + kq;
  const float* wrow = W + (size_t)(n0 + r) * 257 + kq;
  float acc[4][4] = {};
  for (int k0 = 0; k0 < 256; k0 += 32) {
    float4 a0 = *reinterpret_cast<const float4*>(xrow + k0);
    float4 a1 = *reinterpret_cast<const float4*>(xrow + k0 + 4);
    float bv[8];
#pragma unroll
    for (int u = 0; u < 8; ++u) bv[u] = wrow[k0 + u];
    if (k0 != 0) __syncthreads();
    As[kq+0][r]=a0.x; As[kq+1][r]=a0.y; As[kq+2][r]=a0.z; As[kq+3][r]=a0.w;
    As[kq+4][r]=a1.x; As[kq+5][r]=a1.y; As[kq+6][r]=a1.z; As[kq+7][r]=a1.w;
#pragma unroll
    for (int u = 0; u < 8; ++u) Bs[kq+u][r] = bv[u];
    __syncthreads();
#pragma unroll
    for (int kk = 0; kk < 32; ++kk) {
      float4 av = *reinterpret_cast<const float4*>(&As[kk][ty*4]);
      float4 bw = *reinterpret_cast<const float4*>(&Bs[kk][tx*4]);
      const float aa[4] = {av.x, av.y, av.z, av.w};
      const float bbv[4] = {bw.x, bw.y, bw.z, bw.w};
#pragma unroll
      for (int i = 0; i < 4; ++i)
#pragma unroll
        for (int j = 0; j < 4; ++j) acc[i][j] += aa[i] * bbv[j];
    }
  }
  const int col = n0 + tx * 4;
  float bsum[4];
#pragma unroll
  for (int j = 0; j < 4; ++j) bsum[j] = bih[col + j] + bhh[col + j];
#pragma unroll
  for (int i = 0; i < 4; ++i) {
    float4 o;
    o.x = acc[i][0] + bsum[0];
    o.y = acc[i][1] + bsum[1];
    o.z = acc[i][2] + bsum[2];
    o.w = acc[i][3] + bsum[3];
    *reinterpret_cast<float4*>(&G[(size_t)(m0 + ty*4 + i) * 256 + col]) = o;
  }
}

// P[b*Tc+tt] = x[b, t0+tt, :] @ w21 + bias2.  One wave per row, 4 rows/block.
__global__ __launch_bounds__(256) void pz_kernel(const float* __restrict__ X,
                                                 const float* __restrict__ w21,
                                                 const float* __restrict__ bias2,
                                                 float* __restrict__ P,
                                                 int t0, int Tc) {
  const int r = blockIdx.x * 4 + (threadIdx.x >> 6);
  const int lane = threadIdx.x & 63;
  const int bb = r / Tc;
  const int tt = r - bb * Tc;
  const float4 xv = *reinterpret_cast<const float4*>(
      &X[((size_t)(bb * TT + t0 + tt)) * 256 + lane * 4]);
  const float4 wv = *reinterpret_cast<const float4*>(&w21[lane * 4]);
  float s = xv.x*wv.x + xv.y*wv.y + xv.z*wv.z + xv.w*wv.w;
#pragma unroll
  for (int o = 32; o; o >>= 1) s += __shfl_xor(s, o);
  if (lane == 0) P[r] = s + bias2[0];
}

// Serial recurrence: ONE WAVE per batch row, lane l owns hidden unit l and
// ALL FOUR gates (i,f,g,o). Fits in arch VGPRs because Whh is held as packed
// fp16 (128 VGPRs); dots via full-rate v_dot2_f32_f16 (fp32 accumulate).
// Everything else fp32: G, c/h state, pz (DPP-reduced from REGISTER h, exact).
// No s_barrier, no shfl of state: c/h update is lane-local. h broadcast = 8
// uniform ds_read_b128 of fp16 h. 8 independent waves per block (8 rows) give
// 2 waves/SIMD of uncoupled TLP (R6 showed barrier-COUPLED TLP regresses).
__global__ __launch_bounds__(512, 2) void lstm_seq5(
    const float* __restrict__ G, const float* __restrict__ P,
    const float* __restrict__ Wih, const float* __restrict__ Whh,
    const float* __restrict__ w22, float* __restrict__ Z,
    float* __restrict__ hq, float* __restrict__ cq, int t0, int Tc) {
  const int tid = threadIdx.x;
  const int wv  = tid >> 6;          // wave in block = row slot
  const int l   = tid & 63;          // hidden unit
  const int b   = blockIdx.x * 8 + wv;
  __shared__ __align__(16) _Float16 hsm[8][64];

  // Whh rows {l, 64+l, 128+l, 192+l} as fp16 pairs: 4*16 = 64 dwords = 128 VGPR.
  v2h wh[4][32];
#pragma unroll
  for (int q = 0; q < 4; ++q) {
#pragma unroll
    for (int j = 0; j < 16; ++j) {
      float4 v = *reinterpret_cast<const float4*>(&Whh[(size_t)(q*64 + l)*64 + 4*j]);
      v2h pA, pB;
      pA.x = (_Float16)v.x; pA.y = (_Float16)v.y;
      pB.x = (_Float16)v.z; pB.y = (_Float16)v.w;
      wh[q][2*j] = pA; wh[q][2*j+1] = pB;
    }
  }
  float wihL[4];
#pragma unroll
  for (int q = 0; q < 4; ++q) wihL[q] = Wih[(size_t)(q*64 + l)*257 + 256];
  const float w22r = w22[l];

  float h = 0.f, c = 0.f;
  if (t0 != 0) { h = hq[b * 64 + l]; c = cq[b * 64 + l]; }
  hsm[wv][l] = (_Float16)h;
  asm volatile("s_waitcnt lgkmcnt(0)" ::: "memory");
  __builtin_amdgcn_wave_barrier();

  const float* Gb = G + (size_t)b * Tc * 256 + l;   // + gate offset q*64
  const float* Pb = P + (size_t)b * Tc;
  float* Zb = Z + (size_t)b * TT + t0;

  // Prefetch ring, distance 4 (static indices via full unroll).
  float gr[4][4], pr[4];   // gr[slot][gate]
#pragma unroll
  for (int u = 0; u < 4; ++u) {
#pragma unroll
    for (int q = 0; q < 4; ++q) gr[u][q] = Gb[(size_t)u * 256 + q * 64];
    pr[u] = Pb[u];
  }

  for (int tt = 0; tt < Tc; tt += 4) {
    float zs[4];
#pragma unroll
    for (int uu = 0; uu < 4; ++uu) {
      const int step = tt + uu;
      const float gx0 = gr[uu][0], gx1 = gr[uu][1];
      const float gx2 = gr[uu][2], gx3 = gr[uu][3];
      const float p0 = pr[uu];
      int pf = step + 4; if (pf > Tc - 1) pf = Tc - 1;
#pragma unroll
      for (int q = 0; q < 4; ++q) gr[uu][q] = Gb[(size_t)pf * 256 + q * 64];
      pr[uu] = Pb[pf];

      // pz from REGISTER h (fp32, exact w22 dot), off the LDS path
      const float tot = wave_sum64(h * w22r);
      const float pz = fsig(tot + p0);

      // 4 dots: h (fp16 LDS broadcast, 8 x b128) . Whh rows (fp16 in VGPRs)
      float d0a=0.f,d0b=0.f,d1a=0.f,d1b=0.f,d2a=0.f,d2b=0.f,d3a=0.f,d3b=0.f;
      const uint4* hp = reinterpret_cast<const uint4*>(hsm[wv]);
#pragma unroll
      for (int jj = 0; jj < 8; ++jj) {
        const uint4 uq = hp[jj];
        const v2h ha = __builtin_bit_cast(v2h, uq.x);
        const v2h hb = __builtin_bit_cast(v2h, uq.y);
        const v2h hc = __builtin_bit_cast(v2h, uq.z);
        const v2h hd = __builtin_bit_cast(v2h, uq.w);
        d0a = FDOT2(ha, wh[0][4*jj+0], d0a); d0b = FDOT2(hb, wh[0][4*jj+1], d0b);
        d0a = FDOT2(hc, wh[0][4*jj+2], d0a); d0b = FDOT2(hd, wh[0][4*jj+3], d0b);
        d1a = FDOT2(ha, wh[1][4*jj+0], d1a); d1b = FDOT2(hb, wh[1][4*jj+1], d1b);
        d1a = FDOT2(hc, wh[1][4*jj+2], d1a); d1b = FDOT2(hd, wh[1][4*jj+3], d1b);
        d2a = FDOT2(ha, wh[2][4*jj+0], d2a); d2b = FDOT2(hb, wh[2][4*jj+1], d2b);
        d2a = FDOT2(hc, wh[2][4*jj+2], d2a); d2b = FDOT2(hd, wh[2][4*jj+3], d2b);
        d3a = FDOT2(ha, wh[3][4*jj+0], d3a); d3b = FDOT2(hb, wh[3][4*jj+1], d3b);
        d3a = FDOT2(hc, wh[3][4*jj+2], d3a); d3b = FDOT2(hd, wh[3][4*jj+3], d3b);
      }
      const float pre0 = gx0 + pz * wihL[0] + (d0a + d0b);
      const float pre1 = gx1 + pz * wihL[1] + (d1a + d1b);
      const float pre2 = gx2 + pz * wihL[2] + (d2a + d2b);
      const float pre3 = gx3 + pz * wihL[3] + (d3a + d3b);

      const float ai = fsig(pre0);
      const float af = fsig(pre1);
      const float ag = ftan(pre2);
      const float ao = fsig(pre3);
      c = af * c + ai * ag;           // lane-local: no cross-lane state moves
      h = ao * ftan(c);

      __builtin_amdgcn_wave_barrier();   // all hsm reads above stay above
      hsm[wv][l] = (_Float16)h;
      asm volatile("s_waitcnt lgkmcnt(0)" ::: "memory");  // write visible
      __builtin_amdgcn_wave_barrier();
      zs[uu] = pz;                    // wave-uniform (post-readlane)
    }
    if (l == 0) {
      float4 zo; zo.x = zs[0]; zo.y = zs[1]; zo.z = zs[2]; zo.w = zs[3];
      *reinterpret_cast<float4*>(&Zb[tt]) = zo;
    }
  }
  hq[b * 64 + l] = h;
  cq[b * 64 + l] = c;
}

// Fully-inline fp32 fallback (only if d_ws is too small for a 64-step chunk).
__global__ __launch_bounds__(256) void lstm_fallback(const float* __restrict__ X,
    const float* __restrict__ w21, const float* __restrict__ w22,
    const float* __restrict__ bias2, const float* __restrict__ Wih,
    const float* __restrict__ Whh, const float* __restrict__ bih,
    const float* __restrict__ bhh, float* __restrict__ Z) {
  const int b = blockIdx.x;
  const int g = threadIdx.x;
  const int lane = g & 63;
  __shared__ __align__(16) float h_s[64];
  __shared__ float act_s[256];
  __shared__ __align__(16) float x_s[256];
  __shared__ __align__(16) float w21_s[256];
  float wh[64];
#pragma unroll
  for (int j = 0; j < 64; j += 4) {
    float4 v = *reinterpret_cast<const float4*>(&Whh[(size_t)g*64 + j]);
    wh[j]=v.x; wh[j+1]=v.y; wh[j+2]=v.z; wh[j+3]=v.w;
  }
  const float wihL = Wih[(size_t)g*257 + 256];
  const float bias = bih[g] + bhh[g];
  const float b2 = bias2[0];
  const float w22r = w22[lane];
  w21_s[g] = w21[g];
  if (g < 64) h_s[g] = 0.f;
  float c = 0.f;
  __syncthreads();
  const float* Wr = Wih + (size_t)g * 257;
  for (int t = 0; t < TT; ++t) {
    x_s[g] = X[((size_t)b*TT + t)*256 + g];
    __syncthreads();
    float pv = h_s[lane] * w22r;
    {
      const float4 xq = *reinterpret_cast<const float4*>(&x_s[lane*4]);
      const float4 wq = *reinterpret_cast<const float4*>(&w21_s[lane*4]);
      pv += xq.x*wq.x + xq.y*wq.y + xq.z*wq.z + xq.w*wq.w;
    }
#pragma unroll
    for (int o = 32; o; o >>= 1) pv += __shfl_xor(pv, o);
    const float pz = fsig(pv + b2);
    float a0=0.f, a1=0.f, a2=0.f, a3=0.f;
#pragma unroll
    for (int j = 0; j < 64; j += 4) {
      float4 hv = *reinterpret_cast<const float4*>(&h_s[j]);
      a0 += hv.x*wh[j]; a1 += hv.y*wh[j+1]; a2 += hv.z*wh[j+2]; a3 += hv.w*wh[j+3];
    }
    float xd0=0.f, xd1=0.f, xd2=0.f, xd3=0.f;
    for (int k = 0; k < 256; k += 4) {
      const float4 xq = *reinterpret_cast<const float4*>(&x_s[k]);
      xd0 += xq.x*Wr[k]; xd1 += xq.y*Wr[k+1]; xd2 += xq.z*Wr[k+2]; xd3 += xq.w*Wr[k+3];
    }
    const float pre = bias + pz*wihL + ((a0+a1)+(a2+a3)) + ((xd0+xd1)+(xd2+xd3));
    act_s[g] = ((g >> 6) == 2) ? ftan(pre) : fsig(pre);
    if (g == 0) Z[(size_t)b*TT + t] = pz;
    __syncthreads();
    if (g < 64) {
      const float iv = act_s[g], fv = act_s[64+g], gv = act_s[128+g], ov = act_s[192+g];
      c = fv*c + iv*gv;
      h_s[g] = ov * ftan(c);
    }
    __syncthreads();
  }
}

extern "C" void kernel_launch(void* const* d_in, const int* in_sizes, int n_in,
                              void* d_out, int out_size, void* d_ws, size_t ws_size,
                              hipStream_t stream) {
  const float* X     = (const float*)d_in[0];  // [64,2048,256]
  const float* w21   = (const float*)d_in[1];  // [256]
  const float* w22   = (const float*)d_in[2];  // [64]
  const float* bias2 = (const float*)d_in[3];  // [1]
  const float* Wih   = (const float*)d_in[4];  // [256,257]
  const float* Whh   = (const float*)d_in[5];  // [256,64]
  const float* bih   = (const float*)d_in[6];  // [256]
  const float* bhh   = (const float*)d_in[7];  // [256]
  float* Z = (float*)d_out;                    // [64,2048]

  int Tc = 0;
  for (int cand = 2048; cand >= 64; cand >>= 1) {
    size_t need = (size_t)cand * (64*256*4 + 64*4) + 2*64*64*4;
    if (ws_size >= need) { Tc = cand; break; }
  }
  if (Tc == 0) {
    lstm_fallback<<<dim3(64), dim3(256), 0, stream>>>(X, w21, w22, bias2, Wih, Whh, bih, bhh, Z);
    return;
  }
  float* Gbuf = (float*)d_ws;                       // [64*Tc, 256]
  float* Pbuf = Gbuf + (size_t)64 * Tc * 256;       // [64*Tc]
  float* hq   = Pbuf + (size_t)64 * Tc;             // [64,64]
  float* cq   = hq + 64 * 64;                       // [64,64]
  for (int t0 = 0; t0 < 2048; t0 += Tc) {
    gates_gemm<<<dim3(Tc, 4), dim3(256), 0, stream>>>(X, Wih, bih, bhh, Gbuf, t0, Tc);
    pz_kernel<<<dim3(16 * Tc), dim3(256), 0, stream>>>(X, w21, bias2, Pbuf, t0, Tc);
    lstm_seq5<<<dim3(BB / 8), dim3(512), 0, stream>>>(
        Gbuf, Pbuf, Wih, Whh, w22, Z, hq, cq, t0, Tc);
  }
}

// Round 8
// 1906.786 us; speedup vs baseline: 1.0162x; 1.0162x over previous
//
#include <hip/hip_runtime.h>

#define TT 2048
#define BB 64

typedef _Float16 v2h __attribute__((ext_vector_type(2)));

__device__ __forceinline__ float frcp(float x) { return __builtin_amdgcn_rcpf(x); }
__device__ __forceinline__ float fsig(float x) { return frcp(1.f + __expf(-x)); }
__device__ __forceinline__ float ftan(float x) { return 1.f - 2.f * frcp(1.f + __expf(2.f * x)); }

#if __has_builtin(__builtin_amdgcn_fdot2)
#define FDOT2(a, b, c) __builtin_amdgcn_fdot2((a), (b), (c), false)
#else
#define FDOT2(a, b, c) ((c) + (float)(a).x * (float)(b).x + (float)(a).y * (float)(b).y)
#endif

// Canonical GCN wave64 sum-reduction via DPP (verified R4/R5/R7):
// row_shr:1,2,4,8 then row_bcast:15, row_bcast:31; total lands in lane 63.
#define DPPADD(x, ctrl)                                                        \
  (x) += __builtin_bit_cast(float, __builtin_amdgcn_update_dpp(                \
             0, __builtin_bit_cast(int, (x)), (ctrl), 0xf, 0xf, true))

__device__ __forceinline__ float wave_sum64(float x) {
  DPPADD(x, 0x111);  // row_shr:1
  DPPADD(x, 0x112);  // row_shr:2
  DPPADD(x, 0x114);  // row_shr:4
  DPPADD(x, 0x118);  // row_shr:8
  DPPADD(x, 0x142);  // row_bcast:15
  DPPADD(x, 0x143);  // row_bcast:31
  return __builtin_bit_cast(
      float, __builtin_amdgcn_readlane(__builtin_bit_cast(int, x), 63));
}

// G[(b*Tc+tt)*256 + g] = sum_k X[...] * W_ih[g,k] + b_ih[g] + b_hh[g]
// Tiled fp32 GEMM (R5-proven): grid=(Tc,4), block=256, tile 64x64.
__global__ __launch_bounds__(256) void gates_gemm(const float* __restrict__ X,
                                                  const float* __restrict__ W,
                                                  const float* __restrict__ bih,
                                                  const float* __restrict__ bhh,
                                                  float* __restrict__ G,
                                                  int t0, int Tc) {
  __shared__ __align__(16) float As[32][64];  // As[k][m]
  __shared__ __align__(16) float Bs[32][64];  // Bs[k][n]
  const int tid = threadIdx.x;
  const int m0 = blockIdx.x * 64;
  const int n0 = blockIdx.y * 64;
  const int bb = m0 / Tc;
  const int tt0 = m0 - bb * Tc;
  const int tx = tid & 15, ty = tid >> 4;
  const int r  = tid >> 2;
  const int kq = (tid & 3) * 8;
  const float* xrow = X + ((size_t)(bb * TT + t0 + tt0 + r)) * 256 + kq;
  const float* wrow = W + (size_t)(n0 + r) * 257 + kq;
  float acc[4][4] = {};
  for (int k0 = 0; k0 < 256; k0 += 32) {
    float4 a0 = *reinterpret_cast<const float4*>(xrow + k0);
    float4 a1 = *reinterpret_cast<const float4*>(xrow + k0 + 4);
    float bv[8];
#pragma unroll
    for (int u = 0; u < 8; ++u) bv[u] = wrow[k0 + u];
    if (k0 != 0) __syncthreads();
    As[kq+0][r]=a0.x; As[kq+1][r]=a0.y; As[kq+2][r]=a0.z; As[kq+3][r]=a0.w;
    As[kq+4][r]=a1.x; As[kq+5][r]=a1.y; As[kq+6][r]=a1.z; As[kq+7][r]=a1.w;
#pragma unroll
    for (int u = 0; u < 8; ++u) Bs[kq+u][r] = bv[u];
    __syncthreads();
#pragma unroll
    for (int kk = 0; kk < 32; ++kk) {
      float4 av = *reinterpret_cast<const float4*>(&As[kk][ty*4]);
      float4 bw = *reinterpret_cast<const float4*>(&Bs[kk][tx*4]);
      const float aa[4] = {av.x, av.y, av.z, av.w};
      const float bbv[4] = {bw.x, bw.y, bw.z, bw.w};
#pragma unroll
      for (int i = 0; i < 4; ++i)
#pragma unroll
        for (int j = 0; j < 4; ++j) acc[i][j] += aa[i] * bbv[j];
    }
  }
  const int col = n0 + tx * 4;
  float bsum[4];
#pragma unroll
  for (int j = 0; j < 4; ++j) bsum[j] = bih[col + j] + bhh[col + j];
#pragma unroll
  for (int i = 0; i < 4; ++i) {
    float4 o;
    o.x = acc[i][0] + bsum[0];
    o.y = acc[i][1] + bsum[1];
    o.z = acc[i][2] + bsum[2];
    o.w = acc[i][3] + bsum[3];
    *reinterpret_cast<float4*>(&G[(size_t)(m0 + ty*4 + i) * 256 + col]) = o;
  }
}

// P[b*Tc+tt] = x[b, t0+tt, :] @ w21 + bias2.  One wave per row, 4 rows/block.
__global__ __launch_bounds__(256) void pz_kernel(const float* __restrict__ X,
                                                 const float* __restrict__ w21,
                                                 const float* __restrict__ bias2,
                                                 float* __restrict__ P,
                                                 int t0, int Tc) {
  const int r = blockIdx.x * 4 + (threadIdx.x >> 6);
  const int lane = threadIdx.x & 63;
  const int bb = r / Tc;
  const int tt = r - bb * Tc;
  const float4 xv = *reinterpret_cast<const float4*>(
      &X[((size_t)(bb * TT + t0 + tt)) * 256 + lane * 4]);
  const float4 wv = *reinterpret_cast<const float4*>(&w21[lane * 4]);
  float s = xv.x*wv.x + xv.y*wv.y + xv.z*wv.z + xv.w*wv.w;
#pragma unroll
  for (int o = 32; o; o >>= 1) s += __shfl_xor(s, o);
  if (lane == 0) P[r] = s + bias2[0];
}

// Serial recurrence: ONE WAVE per batch row, lane l owns hidden unit l and
// ALL FOUR gates. Whh as packed fp16 (128 VGPRs) + v_dot2_f32_f16 -- R7
// PROVED this hits the same 2^-8 absmax floor as fp32. R7's perf failure was
// launch_bounds(512,2) hard-capping VGPRs at 128 (weights spilled). Fix:
// (512,1) -> ~220 VGPRs allocated, still <=256 so HW runs 2 waves/SIMD of
// UNCOUPLED TLP (no s_barrier anywhere; R6 showed coupled TLP regresses).
// c/h lane-local; pz DPP-reduced from fp32 register h (exact); h broadcast =
// 8 uniform ds_read_b128 of same-wave-ordered LDS (no waitcnt stall needed).
__global__ __launch_bounds__(512, 1) void lstm_seq6(
    const float* __restrict__ G, const float* __restrict__ P,
    const float* __restrict__ Wih, const float* __restrict__ Whh,
    const float* __restrict__ w22, float* __restrict__ Z,
    float* __restrict__ hq, float* __restrict__ cq, int t0, int Tc) {
  const int tid = threadIdx.x;
  const int wv  = tid >> 6;          // wave in block = row slot
  const int l   = tid & 63;          // hidden unit
  const int b   = blockIdx.x * 8 + wv;
  __shared__ __align__(16) _Float16 hsm[8][64];

  // Whh rows {l, 64+l, 128+l, 192+l} as fp16 pairs: 128 VGPRs.
  v2h wh[4][32];
#pragma unroll
  for (int q = 0; q < 4; ++q) {
#pragma unroll
    for (int j = 0; j < 16; ++j) {
      float4 v = *reinterpret_cast<const float4*>(&Whh[(size_t)(q*64 + l)*64 + 4*j]);
      v2h pA, pB;
      pA.x = (_Float16)v.x; pA.y = (_Float16)v.y;
      pB.x = (_Float16)v.z; pB.y = (_Float16)v.w;
      wh[q][2*j] = pA; wh[q][2*j+1] = pB;
    }
  }
  float wihL[4];
#pragma unroll
  for (int q = 0; q < 4; ++q) wihL[q] = Wih[(size_t)(q*64 + l)*257 + 256];
  const float w22r = w22[l];

  float h = 0.f, c = 0.f;
  if (t0 != 0) { h = hq[b * 64 + l]; c = cq[b * 64 + l]; }
  hsm[wv][l] = (_Float16)h;
  __builtin_amdgcn_wave_barrier();

  const float* Gb = G + (size_t)b * Tc * 256 + l;   // + gate offset q*64
  const float* Pb = P + (size_t)b * Tc;
  float* Zb = Z + (size_t)b * TT + t0;

  // Prefetch ring, distance 4 (static indices via full unroll).
  float gr[4][4], pr[4];   // gr[slot][gate]
#pragma unroll
  for (int u = 0; u < 4; ++u) {
    const float* Gt = Gb + (size_t)u * 256;
#pragma unroll
    for (int q = 0; q < 4; ++q) gr[u][q] = Gt[q * 64];
    pr[u] = Pb[u];
  }

  for (int tt = 0; tt < Tc; tt += 4) {
    float zs[4];
#pragma unroll
    for (int uu = 0; uu < 4; ++uu) {
      const int step = tt + uu;
      const float gx0 = gr[uu][0], gx1 = gr[uu][1];
      const float gx2 = gr[uu][2], gx3 = gr[uu][3];
      const float p0 = pr[uu];
      int pf = step + 4; if (pf > Tc - 1) pf = Tc - 1;
      {
        const float* Gt = Gb + (size_t)pf * 256;
#pragma unroll
        for (int q = 0; q < 4; ++q) gr[uu][q] = Gt[q * 64];
        pr[uu] = Pb[pf];
      }

      // issue h broadcast reads first (latency overlaps the pz DPP chain)
      uint4 hv[8];
      const uint4* hp = reinterpret_cast<const uint4*>(hsm[wv]);
#pragma unroll
      for (int jj = 0; jj < 8; ++jj) hv[jj] = hp[jj];

      // pz from fp32 REGISTER h (exact w22 dot), off the LDS path
      const float tot = wave_sum64(h * w22r);
      const float pz = fsig(tot + p0);

      // 4 dots: h (fp16 LDS broadcast) . Whh rows (fp16 pairs in VGPRs)
      float d0a=0.f,d0b=0.f,d1a=0.f,d1b=0.f,d2a=0.f,d2b=0.f,d3a=0.f,d3b=0.f;
#pragma unroll
      for (int jj = 0; jj < 8; ++jj) {
        const v2h ha = __builtin_bit_cast(v2h, hv[jj].x);
        const v2h hb = __builtin_bit_cast(v2h, hv[jj].y);
        const v2h hc = __builtin_bit_cast(v2h, hv[jj].z);
        const v2h hd = __builtin_bit_cast(v2h, hv[jj].w);
        d0a = FDOT2(ha, wh[0][4*jj+0], d0a); d0b = FDOT2(hb, wh[0][4*jj+1], d0b);
        d0a = FDOT2(hc, wh[0][4*jj+2], d0a); d0b = FDOT2(hd, wh[0][4*jj+3], d0b);
        d1a = FDOT2(ha, wh[1][4*jj+0], d1a); d1b = FDOT2(hb, wh[1][4*jj+1], d1b);
        d1a = FDOT2(hc, wh[1][4*jj+2], d1a); d1b = FDOT2(hd, wh[1][4*jj+3], d1b);
        d2a = FDOT2(ha, wh[2][4*jj+0], d2a); d2b = FDOT2(hb, wh[2][4*jj+1], d2b);
        d2a = FDOT2(hc, wh[2][4*jj+2], d2a); d2b = FDOT2(hd, wh[2][4*jj+3], d2b);
        d3a = FDOT2(ha, wh[3][4*jj+0], d3a); d3b = FDOT2(hb, wh[3][4*jj+1], d3b);
        d3a = FDOT2(hc, wh[3][4*jj+2], d3a); d3b = FDOT2(hd, wh[3][4*jj+3], d3b);
      }
      const float pre0 = gx0 + pz * wihL[0] + (d0a + d0b);
      const float pre1 = gx1 + pz * wihL[1] + (d1a + d1b);
      const float pre2 = gx2 + pz * wihL[2] + (d2a + d2b);
      const float pre3 = gx3 + pz * wihL[3] + (d3a + d3b);

      const float ai = fsig(pre0);
      const float af = fsig(pre1);
      const float ag = ftan(pre2);
      const float ao = fsig(pre3);
      c = af * c + ai * ag;           // lane-local: no cross-lane state moves
      h = ao * ftan(c);

      __builtin_amdgcn_wave_barrier();   // all hsm reads above stay above
      hsm[wv][l] = (_Float16)h;          // same-wave LDS: in-order, no waitcnt
      __builtin_amdgcn_wave_barrier();
      zs[uu] = pz;                    // wave-uniform (post-readlane)
    }
    if (l == 0) {
      float4 zo; zo.x = zs[0]; zo.y = zs[1]; zo.z = zs[2]; zo.w = zs[3];
      *reinterpret_cast<float4*>(&Zb[tt]) = zo;
    }
  }
  hq[b * 64 + l] = h;
  cq[b * 64 + l] = c;
}

// Fully-inline fp32 fallback (only if d_ws is too small for a 64-step chunk).
__global__ __launch_bounds__(256) void lstm_fallback(const float* __restrict__ X,
    const float* __restrict__ w21, const float* __restrict__ w22,
    const float* __restrict__ bias2, const float* __restrict__ Wih,
    const float* __restrict__ Whh, const float* __restrict__ bih,
    const float* __restrict__ bhh, float* __restrict__ Z) {
  const int b = blockIdx.x;
  const int g = threadIdx.x;
  const int lane = g & 63;
  __shared__ __align__(16) float h_s[64];
  __shared__ float act_s[256];
  __shared__ __align__(16) float x_s[256];
  __shared__ __align__(16) float w21_s[256];
  float wh[64];
#pragma unroll
  for (int j = 0; j < 64; j += 4) {
    float4 v = *reinterpret_cast<const float4*>(&Whh[(size_t)g*64 + j]);
    wh[j]=v.x; wh[j+1]=v.y; wh[j+2]=v.z; wh[j+3]=v.w;
  }
  const float wihL = Wih[(size_t)g*257 + 256];
  const float bias = bih[g] + bhh[g];
  const float b2 = bias2[0];
  const float w22r = w22[lane];
  w21_s[g] = w21[g];
  if (g < 64) h_s[g] = 0.f;
  float c = 0.f;
  __syncthreads();
  const float* Wr = Wih + (size_t)g * 257;
  for (int t = 0; t < TT; ++t) {
    x_s[g] = X[((size_t)b*TT + t)*256 + g];
    __syncthreads();
    float pv = h_s[lane] * w22r;
    {
      const float4 xq = *reinterpret_cast<const float4*>(&x_s[lane*4]);
      const float4 wq = *reinterpret_cast<const float4*>(&w21_s[lane*4]);
      pv += xq.x*wq.x + xq.y*wq.y + xq.z*wq.z + xq.w*wq.w;
    }
#pragma unroll
    for (int o = 32; o; o >>= 1) pv += __shfl_xor(pv, o);
    const float pz = fsig(pv + b2);
    float a0=0.f, a1=0.f, a2=0.f, a3=0.f;
#pragma unroll
    for (int j = 0; j < 64; j += 4) {
      float4 hv = *reinterpret_cast<const float4*>(&h_s[j]);
      a0 += hv.x*wh[j]; a1 += hv.y*wh[j+1]; a2 += hv.z*wh[j+2]; a3 += hv.w*wh[j+3];
    }
    float xd0=0.f, xd1=0.f, xd2=0.f, xd3=0.f;
    for (int k = 0; k < 256; k += 4) {
      const float4 xq = *reinterpret_cast<const float4*>(&x_s[k]);
      xd0 += xq.x*Wr[k]; xd1 += xq.y*Wr[k+1]; xd2 += xq.z*Wr[k+2]; xd3 += xq.w*Wr[k+3];
    }
    const float pre = bias + pz*wihL + ((a0+a1)+(a2+a3)) + ((xd0+xd1)+(xd2+xd3));
    act_s[g] = ((g >> 6) == 2) ? ftan(pre) : fsig(pre);
    if (g == 0) Z[(size_t)b*TT + t] = pz;
    __syncthreads();
    if (g < 64) {
      const float iv = act_s[g], fv = act_s[64+g], gv = act_s[128+g], ov = act_s[192+g];
      c = fv*c + iv*gv;
      h_s[g] = ov * ftan(c);
    }
    __syncthreads();
  }
}

extern "C" void kernel_launch(void* const* d_in, const int* in_sizes, int n_in,
                              void* d_out, int out_size, void* d_ws, size_t ws_size,
                              hipStream_t stream) {
  const float* X     = (const float*)d_in[0];  // [64,2048,256]
  const float* w21   = (const float*)d_in[1];  // [256]
  const float* w22   = (const float*)d_in[2];  // [64]
  const float* bias2 = (const float*)d_in[3];  // [1]
  const float* Wih   = (const float*)d_in[4];  // [256,257]
  const float* Whh   = (const float*)d_in[5];  // [256,64]
  const float* bih   = (const float*)d_in[6];  // [256]
  const float* bhh   = (const float*)d_in[7];  // [256]
  float* Z = (float*)d_out;                    // [64,2048]

  int Tc = 0;
  for (int cand = 2048; cand >= 64; cand >>= 1) {
    size_t need = (size_t)cand * (64*256*4 + 64*4) + 2*64*64*4;
    if (ws_size >= need) { Tc = cand; break; }
  }
  if (Tc == 0) {
    lstm_fallback<<<dim3(64), dim3(256), 0, stream>>>(X, w21, w22, bias2, Wih, Whh, bih, bhh, Z);
    return;
  }
  float* Gbuf = (float*)d_ws;                       // [64*Tc, 256]
  float* Pbuf = Gbuf + (size_t)64 * Tc * 256;       // [64*Tc]
  float* hq   = Pbuf + (size_t)64 * Tc;             // [64,64]
  float* cq   = hq + 64 * 64;                       // [64,64]
  for (int t0 = 0; t0 < 2048; t0 += Tc) {
    gates_gemm<<<dim3(Tc, 4), dim3(256), 0, stream>>>(X, Wih, bih, bhh, Gbuf, t0, Tc);
    pz_kernel<<<dim3(16 * Tc), dim3(256), 0, stream>>>(X, w21, bias2, Pbuf, t0, Tc);
    lstm_seq6<<<dim3(BB / 8), dim3(512), 0, stream>>>(
        Gbuf, Pbuf, Wih, Whh, w22, Z, hq, cq, t0, Tc);
  }
}

// Round 9
// 1194.068 us; speedup vs baseline: 1.6228x; 1.5969x over previous
//
#include <hip/hip_runtime.h>

#define TT 2048
#define BB 64

typedef _Float16 v2h __attribute__((ext_vector_type(2)));

__device__ __forceinline__ float frcp(float x) { return __builtin_amdgcn_rcpf(x); }
__device__ __forceinline__ float fsig(float x) { return frcp(1.f + __expf(-x)); }
__device__ __forceinline__ float ftan(float x) { return 1.f - 2.f * frcp(1.f + __expf(2.f * x)); }

#if __has_builtin(__builtin_amdgcn_fdot2)
#define FDOT2(a, b, c) __builtin_amdgcn_fdot2((a), (b), (c), false)
#else
#define FDOT2(a, b, c) ((c) + (float)(a).x * (float)(b).x + (float)(a).y * (float)(b).y)
#endif

// Canonical GCN wave64 sum-reduction via DPP (verified R4/R5/R7/R8):
// row_shr:1,2,4,8 then row_bcast:15, row_bcast:31; total lands in lane 63.
#define DPPADD(x, ctrl)                                                        \
  (x) += __builtin_bit_cast(float, __builtin_amdgcn_update_dpp(                \
             0, __builtin_bit_cast(int, (x)), (ctrl), 0xf, 0xf, true))

__device__ __forceinline__ float wave_sum64(float x) {
  DPPADD(x, 0x111);  // row_shr:1
  DPPADD(x, 0x112);  // row_shr:2
  DPPADD(x, 0x114);  // row_shr:4
  DPPADD(x, 0x118);  // row_shr:8
  DPPADD(x, 0x142);  // row_bcast:15
  DPPADD(x, 0x143);  // row_bcast:31
  return __builtin_bit_cast(
      float, __builtin_amdgcn_readlane(__builtin_bit_cast(int, x), 63));
}

// G[(b*Tc+tt)*256 + g] = sum_k X[...] * W_ih[g,k] + b_ih[g] + b_hh[g]
// Tiled fp32 GEMM (R5-proven): grid=(Tc,4), block=256, tile 64x64.
__global__ __launch_bounds__(256) void gates_gemm(const float* __restrict__ X,
                                                  const float* __restrict__ W,
                                                  const float* __restrict__ bih,
                                                  const float* __restrict__ bhh,
                                                  float* __restrict__ G,
                                                  int t0, int Tc) {
  __shared__ __align__(16) float As[32][64];  // As[k][m]
  __shared__ __align__(16) float Bs[32][64];  // Bs[k][n]
  const int tid = threadIdx.x;
  const int m0 = blockIdx.x * 64;
  const int n0 = blockIdx.y * 64;
  const int bb = m0 / Tc;
  const int tt0 = m0 - bb * Tc;
  const int tx = tid & 15, ty = tid >> 4;
  const int r  = tid >> 2;
  const int kq = (tid & 3) * 8;
  const float* xrow = X + ((size_t)(bb * TT + t0 + tt0 + r)) * 256 + kq;
  const float* wrow = W + (size_t)(n0 + r) * 257 + kq;
  float acc[4][4] = {};
  for (int k0 = 0; k0 < 256; k0 += 32) {
    float4 a0 = *reinterpret_cast<const float4*>(xrow + k0);
    float4 a1 = *reinterpret_cast<const float4*>(xrow + k0 + 4);
    float bv[8];
#pragma unroll
    for (int u = 0; u < 8; ++u) bv[u] = wrow[k0 + u];
    if (k0 != 0) __syncthreads();
    As[kq+0][r]=a0.x; As[kq+1][r]=a0.y; As[kq+2][r]=a0.z; As[kq+3][r]=a0.w;
    As[kq+4][r]=a1.x; As[kq+5][r]=a1.y; As[kq+6][r]=a1.z; As[kq+7][r]=a1.w;
#pragma unroll
    for (int u = 0; u < 8; ++u) Bs[kq+u][r] = bv[u];
    __syncthreads();
#pragma unroll
    for (int kk = 0; kk < 32; ++kk) {
      float4 av = *reinterpret_cast<const float4*>(&As[kk][ty*4]);
      float4 bw = *reinterpret_cast<const float4*>(&Bs[kk][tx*4]);
      const float aa[4] = {av.x, av.y, av.z, av.w};
      const float bbv[4] = {bw.x, bw.y, bw.z, bw.w};
#pragma unroll
      for (int i = 0; i < 4; ++i)
#pragma unroll
        for (int j = 0; j < 4; ++j) acc[i][j] += aa[i] * bbv[j];
    }
  }
  const int col = n0 + tx * 4;
  float bsum[4];
#pragma unroll
  for (int j = 0; j < 4; ++j) bsum[j] = bih[col + j] + bhh[col + j];
#pragma unroll
  for (int i = 0; i < 4; ++i) {
    float4 o;
    o.x = acc[i][0] + bsum[0];
    o.y = acc[i][1] + bsum[1];
    o.z = acc[i][2] + bsum[2];
    o.w = acc[i][3] + bsum[3];
    *reinterpret_cast<float4*>(&G[(size_t)(m0 + ty*4 + i) * 256 + col]) = o;
  }
}

// P[b*Tc+tt] = x[b, t0+tt, :] @ w21 + bias2.  One wave per row, 4 rows/block.
__global__ __launch_bounds__(256) void pz_kernel(const float* __restrict__ X,
                                                 const float* __restrict__ w21,
                                                 const float* __restrict__ bias2,
                                                 float* __restrict__ P,
                                                 int t0, int Tc) {
  const int r = blockIdx.x * 4 + (threadIdx.x >> 6);
  const int lane = threadIdx.x & 63;
  const int bb = r / Tc;
  const int tt = r - bb * Tc;
  const float4 xv = *reinterpret_cast<const float4*>(
      &X[((size_t)(bb * TT + t0 + tt)) * 256 + lane * 4]);
  const float4 wv = *reinterpret_cast<const float4*>(&w21[lane * 4]);
  float s = xv.x*wv.x + xv.y*wv.y + xv.z*wv.z + xv.w*wv.w;
#pragma unroll
  for (int o = 32; o; o >>= 1) s += __shfl_xor(s, o);
  if (lane == 0) P[r] = s + bias2[0];
}

// Serial recurrence: ONE WAVE PER BLOCK, one block per batch row (grid=64,
// block=64). Lane l owns hidden unit l and ALL FOUR gates. Whh as packed fp16
// (128 VGPRs) + full-rate v_dot2_f32_f16 (fp32 accumulate); R7/R8 proved this
// precision hits the same 2^-8 absmax floor as fp32. R7/R8 ALSO proved the
// compiler pins 8-wave (512-thread) blocks at 128 arch VGPRs (weights go to
// AGPR/scratch); R2 proved 64-thread blocks get ~184+. So: 64-thread block,
// launch_bounds(64,1) -> budget up to 512 VGPR/wave, we need ~195.
// No s_barrier, no shfl of state; c/h lane-local; pz DPP-reduced from fp32
// register h (exact); h broadcast = 8 uniform ds_read_b128 of fp16 LDS.
__global__ __launch_bounds__(64, 1) void lstm_seq7(
    const float* __restrict__ G, const float* __restrict__ P,
    const float* __restrict__ Wih, const float* __restrict__ Whh,
    const float* __restrict__ w22, float* __restrict__ Z,
    float* __restrict__ hq, float* __restrict__ cq, int t0, int Tc) {
  const int l = threadIdx.x;         // hidden unit
  const int b = blockIdx.x;          // batch row
  __shared__ __align__(16) _Float16 hsm[64];

  // Whh rows {l, 64+l, 128+l, 192+l} as fp16 pairs: 128 VGPRs.
  v2h wh[4][32];
#pragma unroll
  for (int q = 0; q < 4; ++q) {
#pragma unroll
    for (int j = 0; j < 16; ++j) {
      float4 v = *reinterpret_cast<const float4*>(&Whh[(size_t)(q*64 + l)*64 + 4*j]);
      v2h pA, pB;
      pA.x = (_Float16)v.x; pA.y = (_Float16)v.y;
      pB.x = (_Float16)v.z; pB.y = (_Float16)v.w;
      wh[q][2*j] = pA; wh[q][2*j+1] = pB;
    }
  }
  float wihL[4];
#pragma unroll
  for (int q = 0; q < 4; ++q) wihL[q] = Wih[(size_t)(q*64 + l)*257 + 256];
  const float w22r = w22[l];

  float h = 0.f, c = 0.f;
  if (t0 != 0) { h = hq[b * 64 + l]; c = cq[b * 64 + l]; }
  hsm[l] = (_Float16)h;
  __builtin_amdgcn_wave_barrier();

  const float* Gb = G + (size_t)b * Tc * 256 + l;   // + gate offset q*64
  const float* Pb = P + (size_t)b * Tc;
  float* Zb = Z + (size_t)b * TT + t0;

  // Prefetch ring, distance 4 (static indices via full unroll).
  float gr[4][4], pr[4];   // gr[slot][gate]
#pragma unroll
  for (int u = 0; u < 4; ++u) {
    const float* Gt = Gb + (size_t)u * 256;
#pragma unroll
    for (int q = 0; q < 4; ++q) gr[u][q] = Gt[q * 64];
    pr[u] = Pb[u];
  }

  for (int tt = 0; tt < Tc; tt += 4) {
    float zs[4];
#pragma unroll
    for (int uu = 0; uu < 4; ++uu) {
      const int step = tt + uu;
      const float gx0 = gr[uu][0], gx1 = gr[uu][1];
      const float gx2 = gr[uu][2], gx3 = gr[uu][3];
      const float p0 = pr[uu];
      int pf = step + 4; if (pf > Tc - 1) pf = Tc - 1;
      {
        const float* Gt = Gb + (size_t)pf * 256;
#pragma unroll
        for (int q = 0; q < 4; ++q) gr[uu][q] = Gt[q * 64];
        pr[uu] = Pb[pf];
      }

      // pz from fp32 REGISTER h (exact w22 dot), overlaps the LDS reads below
      const float tot = wave_sum64(h * w22r);
      const float pz = fsig(tot + p0);

      // 4 dots: h (fp16 LDS broadcast, 8 x uniform b128) . Whh (fp16 VGPRs)
      float d0a=0.f,d0b=0.f,d1a=0.f,d1b=0.f,d2a=0.f,d2b=0.f,d3a=0.f,d3b=0.f;
      const uint4* hp = reinterpret_cast<const uint4*>(hsm);
#pragma unroll
      for (int jj = 0; jj < 8; ++jj) {
        const uint4 uq = hp[jj];
        const v2h ha = __builtin_bit_cast(v2h, uq.x);
        const v2h hb = __builtin_bit_cast(v2h, uq.y);
        const v2h hc = __builtin_bit_cast(v2h, uq.z);
        const v2h hd = __builtin_bit_cast(v2h, uq.w);
        d0a = FDOT2(ha, wh[0][4*jj+0], d0a); d0b = FDOT2(hb, wh[0][4*jj+1], d0b);
        d0a = FDOT2(hc, wh[0][4*jj+2], d0a); d0b = FDOT2(hd, wh[0][4*jj+3], d0b);
        d1a = FDOT2(ha, wh[1][4*jj+0], d1a); d1b = FDOT2(hb, wh[1][4*jj+1], d1b);
        d1a = FDOT2(hc, wh[1][4*jj+2], d1a); d1b = FDOT2(hd, wh[1][4*jj+3], d1b);
        d2a = FDOT2(ha, wh[2][4*jj+0], d2a); d2b = FDOT2(hb, wh[2][4*jj+1], d2b);
        d2a = FDOT2(hc, wh[2][4*jj+2], d2a); d2b = FDOT2(hd, wh[2][4*jj+3], d2b);
        d3a = FDOT2(ha, wh[3][4*jj+0], d3a); d3b = FDOT2(hb, wh[3][4*jj+1], d3b);
        d3a = FDOT2(hc, wh[3][4*jj+2], d3a); d3b = FDOT2(hd, wh[3][4*jj+3], d3b);
      }
      const float pre0 = gx0 + pz * wihL[0] + (d0a + d0b);
      const float pre1 = gx1 + pz * wihL[1] + (d1a + d1b);
      const float pre2 = gx2 + pz * wihL[2] + (d2a + d2b);
      const float pre3 = gx3 + pz * wihL[3] + (d3a + d3b);

      const float ai = fsig(pre0);
      const float af = fsig(pre1);
      const float ag = ftan(pre2);
      const float ao = fsig(pre3);
      c = af * c + ai * ag;           // lane-local: no cross-lane state moves
      h = ao * ftan(c);

      __builtin_amdgcn_wave_barrier();   // all hsm reads above stay above
      hsm[l] = (_Float16)h;              // same-wave LDS: in-order
      __builtin_amdgcn_wave_barrier();
      zs[uu] = pz;                    // wave-uniform (post-readlane)
    }
    if (l == 0) {
      float4 zo; zo.x = zs[0]; zo.y = zs[1]; zo.z = zs[2]; zo.w = zs[3];
      *reinterpret_cast<float4*>(&Zb[tt]) = zo;
    }
  }
  hq[b * 64 + l] = h;
  cq[b * 64 + l] = c;
}

// Fully-inline fp32 fallback (only if d_ws is too small for a 64-step chunk).
__global__ __launch_bounds__(256) void lstm_fallback(const float* __restrict__ X,
    const float* __restrict__ w21, const float* __restrict__ w22,
    const float* __restrict__ bias2, const float* __restrict__ Wih,
    const float* __restrict__ Whh, const float* __restrict__ bih,
    const float* __restrict__ bhh, float* __restrict__ Z) {
  const int b = blockIdx.x;
  const int g = threadIdx.x;
  const int lane = g & 63;
  __shared__ __align__(16) float h_s[64];
  __shared__ float act_s[256];
  __shared__ __align__(16) float x_s[256];
  __shared__ __align__(16) float w21_s[256];
  float wh[64];
#pragma unroll
  for (int j = 0; j < 64; j += 4) {
    float4 v = *reinterpret_cast<const float4*>(&Whh[(size_t)g*64 + j]);
    wh[j]=v.x; wh[j+1]=v.y; wh[j+2]=v.z; wh[j+3]=v.w;
  }
  const float wihL = Wih[(size_t)g*257 + 256];
  const float bias = bih[g] + bhh[g];
  const float b2 = bias2[0];
  const float w22r = w22[lane];
  w21_s[g] = w21[g];
  if (g < 64) h_s[g] = 0.f;
  float c = 0.f;
  __syncthreads();
  const float* Wr = Wih + (size_t)g * 257;
  for (int t = 0; t < TT; ++t) {
    x_s[g] = X[((size_t)b*TT + t)*256 + g];
    __syncthreads();
    float pv = h_s[lane] * w22r;
    {
      const float4 xq = *reinterpret_cast<const float4*>(&x_s[lane*4]);
      const float4 wq = *reinterpret_cast<const float4*>(&w21_s[lane*4]);
      pv += xq.x*wq.x + xq.y*wq.y + xq.z*wq.z + xq.w*wq.w;
    }
#pragma unroll
    for (int o = 32; o; o >>= 1) pv += __shfl_xor(pv, o);
    const float pz = fsig(pv + b2);
    float a0=0.f, a1=0.f, a2=0.f, a3=0.f;
#pragma unroll
    for (int j = 0; j < 64; j += 4) {
      float4 hv = *reinterpret_cast<const float4*>(&h_s[j]);
      a0 += hv.x*wh[j]; a1 += hv.y*wh[j+1]; a2 += hv.z*wh[j+2]; a3 += hv.w*wh[j+3];
    }
    float xd0=0.f, xd1=0.f, xd2=0.f, xd3=0.f;
    for (int k = 0; k < 256; k += 4) {
      const float4 xq = *reinterpret_cast<const float4*>(&x_s[k]);
      xd0 += xq.x*Wr[k]; xd1 += xq.y*Wr[k+1]; xd2 += xq.z*Wr[k+2]; xd3 += xq.w*Wr[k+3];
    }
    const float pre = bias + pz*wihL + ((a0+a1)+(a2+a3)) + ((xd0+xd1)+(xd2+xd3));
    act_s[g] = ((g >> 6) == 2) ? ftan(pre) : fsig(pre);
    if (g == 0) Z[(size_t)b*TT + t] = pz;
    __syncthreads();
    if (g < 64) {
      const float iv = act_s[g], fv = act_s[64+g], gv = act_s[128+g], ov = act_s[192+g];
      c = fv*c + iv*gv;
      h_s[g] = ov * ftan(c);
    }
    __syncthreads();
  }
}

extern "C" void kernel_launch(void* const* d_in, const int* in_sizes, int n_in,
                              void* d_out, int out_size, void* d_ws, size_t ws_size,
                              hipStream_t stream) {
  const float* X     = (const float*)d_in[0];  // [64,2048,256]
  const float* w21   = (const float*)d_in[1];  // [256]
  const float* w22   = (const float*)d_in[2];  // [64]
  const float* bias2 = (const float*)d_in[3];  // [1]
  const float* Wih   = (const float*)d_in[4];  // [256,257]
  const float* Whh   = (const float*)d_in[5];  // [256,64]
  const float* bih   = (const float*)d_in[6];  // [256]
  const float* bhh   = (const float*)d_in[7];  // [256]
  float* Z = (float*)d_out;                    // [64,2048]

  int Tc = 0;
  for (int cand = 2048; cand >= 64; cand >>= 1) {
    size_t need = (size_t)cand * (64*256*4 + 64*4) + 2*64*64*4;
    if (ws_size >= need) { Tc = cand; break; }
  }
  if (Tc == 0) {
    lstm_fallback<<<dim3(64), dim3(256), 0, stream>>>(X, w21, w22, bias2, Wih, Whh, bih, bhh, Z);
    return;
  }
  float* Gbuf = (float*)d_ws;                       // [64*Tc, 256]
  float* Pbuf = Gbuf + (size_t)64 * Tc * 256;       // [64*Tc]
  float* hq   = Pbuf + (size_t)64 * Tc;             // [64,64]
  float* cq   = hq + 64 * 64;                       // [64,64]
  for (int t0 = 0; t0 < 2048; t0 += Tc) {
    gates_gemm<<<dim3(Tc, 4), dim3(256), 0, stream>>>(X, Wih, bih, bhh, Gbuf, t0, Tc);
    pz_kernel<<<dim3(16 * Tc), dim3(256), 0, stream>>>(X, w21, bias2, Pbuf, t0, Tc);
    lstm_seq7<<<dim3(BB), dim3(64), 0, stream>>>(
        Gbuf, Pbuf, Wih, Whh, w22, Z, hq, cq, t0, Tc);
  }
}

// Round 11
// 1049.068 us; speedup vs baseline: 1.8471x; 1.1382x over previous
//
#include <hip/hip_runtime.h>

#define TT 2048
#define BB 64

typedef _Float16 v2h __attribute__((ext_vector_type(2)));
typedef _Float16 v4h __attribute__((ext_vector_type(4)));
typedef float v4f __attribute__((ext_vector_type(4)));

__device__ __forceinline__ float frcp(float x) { return __builtin_amdgcn_rcpf(x); }
__device__ __forceinline__ float fsig(float x) { return frcp(1.f + __expf(-x)); }
__device__ __forceinline__ float ftan(float x) { return 1.f - 2.f * frcp(1.f + __expf(2.f * x)); }

#if __has_builtin(__builtin_amdgcn_fdot2)
#define FDOT2(a, b, c) __builtin_amdgcn_fdot2((a), (b), (c), false)
#else
#define FDOT2(a, b, c) ((c) + (float)(a).x * (float)(b).x + (float)(a).y * (float)(b).y)
#endif

// Canonical GCN wave64 sum-reduction via DPP (verified R4/R5/R7/R8/R9).
#define DPPADD(x, ctrl)                                                        \
  (x) += __builtin_bit_cast(float, __builtin_amdgcn_update_dpp(                \
             0, __builtin_bit_cast(int, (x)), (ctrl), 0xf, 0xf, true))

__device__ __forceinline__ float wave_sum64(float x) {
  DPPADD(x, 0x111);  // row_shr:1
  DPPADD(x, 0x112);  // row_shr:2
  DPPADD(x, 0x114);  // row_shr:4
  DPPADD(x, 0x118);  // row_shr:8
  DPPADD(x, 0x142);  // row_bcast:15
  DPPADD(x, 0x143);  // row_bcast:31
  return __builtin_bit_cast(
      float, __builtin_amdgcn_readlane(__builtin_bit_cast(int, x), 63));
}

// MFMA gates GEMM: G[(b*Tc+tt)*256 + g] = X_row . W_ih[g,:256] + bih[g]+bhh[g]
// fp16 inputs (numerics proven at the 2^-8 floor by R7/R9), fp32 accumulate.
// Legacy v_mfma_f32_16x16x16f16 (documented layout: A[l&15][(l>>4)*4+e],
// B[(l>>4)*4+e][l&15], D col=l&15 row=(l>>4)*4+j).
// Block 256 thr: tile M=64 x N=128, K-chunks of 32 in LDS (row stride 40 fp16
// -> 2-way bank conflicts only, free). acc = 8 x v4f = 32 VGPRs. grid=(Tc,2).
__global__ __launch_bounds__(256) void gates_gemm_mfma(
    const float* __restrict__ X, const float* __restrict__ W,
    const float* __restrict__ bih, const float* __restrict__ bhh,
    float* __restrict__ G, int t0, int Tc) {
  __shared__ __align__(16) _Float16 Xs[64][40];
  __shared__ __align__(16) _Float16 Ws[128][40];
  const int tid = threadIdx.x;
  const int m0 = blockIdx.x * 64;
  const int n0 = blockIdx.y * 128;
  const int bb = m0 / Tc;
  const int tt0 = m0 - bb * Tc;
  const int w = tid >> 6, l = tid & 63;
  const int lr = l & 15, lk = l >> 4;

  // staging coords: X -> 8 fp16/thread; W -> 16 fp16/thread (scalar loads:
  // W row stride 257 breaks float4 alignment)
  const int srow = tid >> 2, skq = (tid & 3) * 8;
  const int wri = tid >> 1, wkh = (tid & 1) * 16;
  const float* xrow = X + (size_t)(bb * TT + t0 + tt0 + srow) * 256 + skq;
  const float* wrow = W + (size_t)(n0 + wri) * 257 + wkh;

  float bsum[8];
#pragma unroll
  for (int nf = 0; nf < 8; ++nf)
    bsum[nf] = bih[n0 + nf * 16 + lr] + bhh[n0 + nf * 16 + lr];

  v4f acc[8];
#pragma unroll
  for (int nf = 0; nf < 8; ++nf) acc[nf] = (v4f){0.f, 0.f, 0.f, 0.f};

  for (int k0 = 0; k0 < 256; k0 += 32) {
    float xa[8], wa[16];
#pragma unroll
    for (int u = 0; u < 8; ++u) xa[u] = xrow[k0 + u];
#pragma unroll
    for (int u = 0; u < 16; ++u) wa[u] = wrow[k0 + u];
    if (k0 != 0) __syncthreads();
    {
      // pack fp16 pairs -> single b128 stores
      uint xw[4];
#pragma unroll
      for (int u = 0; u < 4; ++u) {
        v2h p; p.x = (_Float16)xa[2*u]; p.y = (_Float16)xa[2*u+1];
        xw[u] = __builtin_bit_cast(uint, p);
      }
      *reinterpret_cast<uint4*>(&Xs[srow][skq]) =
          make_uint4(xw[0], xw[1], xw[2], xw[3]);
      uint ww[8];
#pragma unroll
      for (int u = 0; u < 8; ++u) {
        v2h p; p.x = (_Float16)wa[2*u]; p.y = (_Float16)wa[2*u+1];
        ww[u] = __builtin_bit_cast(uint, p);
      }
      *reinterpret_cast<uint4*>(&Ws[wri][wkh]) =
          make_uint4(ww[0], ww[1], ww[2], ww[3]);
      *reinterpret_cast<uint4*>(&Ws[wri][wkh + 8]) =
          make_uint4(ww[4], ww[5], ww[6], ww[7]);
    }
    __syncthreads();
    const v4h a0 = *reinterpret_cast<const v4h*>(&Xs[w * 16 + lr][lk * 4]);
    const v4h a1 = *reinterpret_cast<const v4h*>(&Xs[w * 16 + lr][16 + lk * 4]);
#pragma unroll
    for (int nf = 0; nf < 8; ++nf) {
      const v4h b0 = *reinterpret_cast<const v4h*>(&Ws[nf * 16 + lr][lk * 4]);
      const v4h b1 = *reinterpret_cast<const v4h*>(&Ws[nf * 16 + lr][16 + lk * 4]);
      acc[nf] = __builtin_amdgcn_mfma_f32_16x16x16f16(a0, b0, acc[nf], 0, 0, 0);
      acc[nf] = __builtin_amdgcn_mfma_f32_16x16x16f16(a1, b1, acc[nf], 0, 0, 0);
    }
  }
  const int grow = m0 + w * 16 + lk * 4;
#pragma unroll
  for (int nf = 0; nf < 8; ++nf) {
#pragma unroll
    for (int j = 0; j < 4; ++j) {
      G[(size_t)(grow + j) * 256 + n0 + nf * 16 + lr] = acc[nf][j] + bsum[nf];
    }
  }
}

// P[b*Tc+tt] = x[b, t0+tt, :] @ w21 + bias2.  One wave per row, 4 rows/block.
__global__ __launch_bounds__(256) void pz_kernel(const float* __restrict__ X,
                                                 const float* __restrict__ w21,
                                                 const float* __restrict__ bias2,
                                                 float* __restrict__ P,
                                                 int t0, int Tc) {
  const int r = blockIdx.x * 4 + (threadIdx.x >> 6);
  const int lane = threadIdx.x & 63;
  const int bb = r / Tc;
  const int tt = r - bb * Tc;
  const float4 xv = *reinterpret_cast<const float4*>(
      &X[((size_t)(bb * TT + t0 + tt)) * 256 + lane * 4]);
  const float4 wv = *reinterpret_cast<const float4*>(&w21[lane * 4]);
  float s = xv.x*wv.x + xv.y*wv.y + xv.z*wv.z + xv.w*wv.w;
#pragma unroll
  for (int o = 32; o; o >>= 1) s += __shfl_xor(s, o);
  if (lane == 0) P[r] = s + bias2[0];
}

// Serial recurrence: ONE WAVE PER BLOCK (R9, best measured: 951us). Unchanged.
__global__ __launch_bounds__(64, 1) void lstm_seq7(
    const float* __restrict__ G, const float* __restrict__ P,
    const float* __restrict__ Wih, const float* __restrict__ Whh,
    const float* __restrict__ w22, float* __restrict__ Z,
    float* __restrict__ hq, float* __restrict__ cq, int t0, int Tc) {
  const int l = threadIdx.x;         // hidden unit
  const int b = blockIdx.x;          // batch row
  __shared__ __align__(16) _Float16 hsm[64];

  v2h wh[4][32];
#pragma unroll
  for (int q = 0; q < 4; ++q) {
#pragma unroll
    for (int j = 0; j < 16; ++j) {
      float4 v = *reinterpret_cast<const float4*>(&Whh[(size_t)(q*64 + l)*64 + 4*j]);
      v2h pA, pB;
      pA.x = (_Float16)v.x; pA.y = (_Float16)v.y;
      pB.x = (_Float16)v.z; pB.y = (_Float16)v.w;
      wh[q][2*j] = pA; wh[q][2*j+1] = pB;
    }
  }
  float wihL[4];
#pragma unroll
  for (int q = 0; q < 4; ++q) wihL[q] = Wih[(size_t)(q*64 + l)*257 + 256];
  const float w22r = w22[l];

  float h = 0.f, c = 0.f;
  if (t0 != 0) { h = hq[b * 64 + l]; c = cq[b * 64 + l]; }
  hsm[l] = (_Float16)h;
  __builtin_amdgcn_wave_barrier();

  const float* Gb = G + (size_t)b * Tc * 256 + l;
  const float* Pb = P + (size_t)b * Tc;
  float* Zb = Z + (size_t)b * TT + t0;

  float gr[4][4], pr[4];
#pragma unroll
  for (int u = 0; u < 4; ++u) {
    const float* Gt = Gb + (size_t)u * 256;
#pragma unroll
    for (int q = 0; q < 4; ++q) gr[u][q] = Gt[q * 64];
    pr[u] = Pb[u];
  }

  for (int tt = 0; tt < Tc; tt += 4) {
    float zs[4];
#pragma unroll
    for (int uu = 0; uu < 4; ++uu) {
      const int step = tt + uu;
      const float gx0 = gr[uu][0], gx1 = gr[uu][1];
      const float gx2 = gr[uu][2], gx3 = gr[uu][3];
      const float p0 = pr[uu];
      int pf = step + 4; if (pf > Tc - 1) pf = Tc - 1;
      {
        const float* Gt = Gb + (size_t)pf * 256;
#pragma unroll
        for (int q = 0; q < 4; ++q) gr[uu][q] = Gt[q * 64];
        pr[uu] = Pb[pf];
      }

      const float tot = wave_sum64(h * w22r);
      const float pz = fsig(tot + p0);

      float d0a=0.f,d0b=0.f,d1a=0.f,d1b=0.f,d2a=0.f,d2b=0.f,d3a=0.f,d3b=0.f;
      const uint4* hp = reinterpret_cast<const uint4*>(hsm);
#pragma unroll
      for (int jj = 0; jj < 8; ++jj) {
        const uint4 uq = hp[jj];
        const v2h ha = __builtin_bit_cast(v2h, uq.x);
        const v2h hb = __builtin_bit_cast(v2h, uq.y);
        const v2h hc = __builtin_bit_cast(v2h, uq.z);
        const v2h hd = __builtin_bit_cast(v2h, uq.w);
        d0a = FDOT2(ha, wh[0][4*jj+0], d0a); d0b = FDOT2(hb, wh[0][4*jj+1], d0b);
        d0a = FDOT2(hc, wh[0][4*jj+2], d0a); d0b = FDOT2(hd, wh[0][4*jj+3], d0b);
        d1a = FDOT2(ha, wh[1][4*jj+0], d1a); d1b = FDOT2(hb, wh[1][4*jj+1], d1b);
        d1a = FDOT2(hc, wh[1][4*jj+2], d1a); d1b = FDOT2(hd, wh[1][4*jj+3], d1b);
        d2a = FDOT2(ha, wh[2][4*jj+0], d2a); d2b = FDOT2(hb, wh[2][4*jj+1], d2b);
        d2a = FDOT2(hc, wh[2][4*jj+2], d2a); d2b = FDOT2(hd, wh[2][4*jj+3], d2b);
        d3a = FDOT2(ha, wh[3][4*jj+0], d3a); d3b = FDOT2(hb, wh[3][4*jj+1], d3b);
        d3a = FDOT2(hc, wh[3][4*jj+2], d3a); d3b = FDOT2(hd, wh[3][4*jj+3], d3b);
      }
      const float pre0 = gx0 + pz * wihL[0] + (d0a + d0b);
      const float pre1 = gx1 + pz * wihL[1] + (d1a + d1b);
      const float pre2 = gx2 + pz * wihL[2] + (d2a + d2b);
      const float pre3 = gx3 + pz * wihL[3] + (d3a + d3b);

      const float ai = fsig(pre0);
      const float af = fsig(pre1);
      const float ag = ftan(pre2);
      const float ao = fsig(pre3);
      c = af * c + ai * ag;
      h = ao * ftan(c);

      __builtin_amdgcn_wave_barrier();
      hsm[l] = (_Float16)h;
      __builtin_amdgcn_wave_barrier();
      zs[uu] = pz;
    }
    if (l == 0) {
      float4 zo; zo.x = zs[0]; zo.y = zs[1]; zo.z = zs[2]; zo.w = zs[3];
      *reinterpret_cast<float4*>(&Zb[tt]) = zo;
    }
  }
  hq[b * 64 + l] = h;
  cq[b * 64 + l] = c;
}

// Fully-inline fp32 fallback (only if d_ws is too small for a 64-step chunk).
__global__ __launch_bounds__(256) void lstm_fallback(const float* __restrict__ X,
    const float* __restrict__ w21, const float* __restrict__ w22,
    const float* __restrict__ bias2, const float* __restrict__ Wih,
    const float* __restrict__ Whh, const float* __restrict__ bih,
    const float* __restrict__ bhh, float* __restrict__ Z) {
  const int b = blockIdx.x;
  const int g = threadIdx.x;
  const int lane = g & 63;
  __shared__ __align__(16) float h_s[64];
  __shared__ float act_s[256];
  __shared__ __align__(16) float x_s[256];
  __shared__ __align__(16) float w21_s[256];
  float wh[64];
#pragma unroll
  for (int j = 0; j < 64; j += 4) {
    float4 v = *reinterpret_cast<const float4*>(&Whh[(size_t)g*64 + j]);
    wh[j]=v.x; wh[j+1]=v.y; wh[j+2]=v.z; wh[j+3]=v.w;
  }
  const float wihL = Wih[(size_t)g*257 + 256];
  const float bias = bih[g] + bhh[g];
  const float b2 = bias2[0];
  const float w22r = w22[lane];
  w21_s[g] = w21[g];
  if (g < 64) h_s[g] = 0.f;
  float c = 0.f;
  __syncthreads();
  const float* Wr = Wih + (size_t)g * 257;
  for (int t = 0; t < TT; ++t) {
    x_s[g] = X[((size_t)b*TT + t)*256 + g];
    __syncthreads();
    float pv = h_s[lane] * w22r;
    {
      const float4 xq = *reinterpret_cast<const float4*>(&x_s[lane*4]);
      const float4 wq = *reinterpret_cast<const float4*>(&w21_s[lane*4]);
      pv += xq.x*wq.x + xq.y*wq.y + xq.z*wq.z + xq.w*wq.w;
    }
#pragma unroll
    for (int o = 32; o; o >>= 1) pv += __shfl_xor(pv, o);
    const float pz = fsig(pv + b2);
    float a0=0.f, a1=0.f, a2=0.f, a3=0.f;
#pragma unroll
    for (int j = 0; j < 64; j += 4) {
      float4 hv = *reinterpret_cast<const float4*>(&h_s[j]);
      a0 += hv.x*wh[j]; a1 += hv.y*wh[j+1]; a2 += hv.z*wh[j+2]; a3 += hv.w*wh[j+3];
    }
    float xd0=0.f, xd1=0.f, xd2=0.f, xd3=0.f;
    for (int k = 0; k < 256; k += 4) {
      const float4 xq = *reinterpret_cast<const float4*>(&x_s[k]);
      xd0 += xq.x*Wr[k]; xd1 += xq.y*Wr[k+1]; xd2 += xq.z*Wr[k+2]; xd3 += xq.w*Wr[k+3];
    }
    const float pre = bias + pz*wihL + ((a0+a1)+(a2+a3)) + ((xd0+xd1)+(xd2+xd3));
    act_s[g] = ((g >> 6) == 2) ? ftan(pre) : fsig(pre);
    if (g == 0) Z[(size_t)b*TT + t] = pz;
    __syncthreads();
    if (g < 64) {
      const float iv = act_s[g], fv = act_s[64+g], gv = act_s[128+g], ov = act_s[192+g];
      c = fv*c + iv*gv;
      h_s[g] = ov * ftan(c);
    }
    __syncthreads();
  }
}

extern "C" void kernel_launch(void* const* d_in, const int* in_sizes, int n_in,
                              void* d_out, int out_size, void* d_ws, size_t ws_size,
                              hipStream_t stream) {
  const float* X     = (const float*)d_in[0];  // [64,2048,256]
  const float* w21   = (const float*)d_in[1];  // [256]
  const float* w22   = (const float*)d_in[2];  // [64]
  const float* bias2 = (const float*)d_in[3];  // [1]
  const float* Wih   = (const float*)d_in[4];  // [256,257]
  const float* Whh   = (const float*)d_in[5];  // [256,64]
  const float* bih   = (const float*)d_in[6];  // [256]
  const float* bhh   = (const float*)d_in[7];  // [256]
  float* Z = (float*)d_out;                    // [64,2048]

  int Tc = 0;
  for (int cand = 2048; cand >= 64; cand >>= 1) {
    size_t need = (size_t)cand * (64*256*4 + 64*4) + 2*64*64*4;
    if (ws_size >= need) { Tc = cand; break; }
  }
  if (Tc == 0) {
    lstm_fallback<<<dim3(64), dim3(256), 0, stream>>>(X, w21, w22, bias2, Wih, Whh, bih, bhh, Z);
    return;
  }
  float* Gbuf = (float*)d_ws;                       // [64*Tc, 256]
  float* Pbuf = Gbuf + (size_t)64 * Tc * 256;       // [64*Tc]
  float* hq   = Pbuf + (size_t)64 * Tc;             // [64,64]
  float* cq   = hq + 64 * 64;                       // [64,64]
  for (int t0 = 0; t0 < 2048; t0 += Tc) {
    gates_gemm_mfma<<<dim3(Tc, 2), dim3(256), 0, stream>>>(X, Wih, bih, bhh,
                                                           Gbuf, t0, Tc);
    pz_kernel<<<dim3(16 * Tc), dim3(256), 0, stream>>>(X, w21, bias2, Pbuf, t0, Tc);
    lstm_seq7<<<dim3(BB), dim3(64), 0, stream>>>(
        Gbuf, Pbuf, Wih, Whh, w22, Z, hq, cq, t0, Tc);
  }
}